// Round 1
// baseline (691.737 us; speedup 1.0000x reference)
//
#include <hip/hip_runtime.h>

#define NN 50000
#define NE 800000

// ---------------------------------------------------------------- histogram
__global__ __launch_bounds__(256) void hist_kernel(const int* __restrict__ dst,
                                                   int* __restrict__ cnt) {
    int i = blockIdx.x * blockDim.x + threadIdx.x;
    if (i < NE) atomicAdd(&cnt[dst[i]], 1);
}

// ------------------------------------------------- single-block exclusive scan
__global__ __launch_bounds__(1024) void scan_kernel(const int* __restrict__ cnt,
                                                    int* __restrict__ row_ptr,
                                                    int* __restrict__ nxt, int n) {
    __shared__ int warp_sums[16];
    int base = 0;
    const int lane = threadIdx.x & 63;
    const int wid = threadIdx.x >> 6;
    for (int start = 0; start < n; start += 1024) {
        int i = start + (int)threadIdx.x;
        int v = (i < n) ? cnt[i] : 0;
        int incl = v;
        #pragma unroll
        for (int off = 1; off < 64; off <<= 1) {
            int t = __shfl_up(incl, off);
            if (lane >= off) incl += t;
        }
        if (lane == 63) warp_sums[wid] = incl;
        __syncthreads();
        if (threadIdx.x < 16) {
            int ws = warp_sums[threadIdx.x];
            #pragma unroll
            for (int off = 1; off < 16; off <<= 1) {
                int t = __shfl_up(ws, off);
                if ((int)threadIdx.x >= off) ws += t;
            }
            warp_sums[threadIdx.x] = ws;  // inclusive over waves
        }
        __syncthreads();
        int wave_off = (wid == 0) ? 0 : warp_sums[wid - 1];
        int excl = base + wave_off + incl - v;
        if (i < n) { row_ptr[i] = excl; nxt[i] = excl; }
        base += warp_sums[15];
        __syncthreads();  // protect warp_sums for next tile
    }
    if (threadIdx.x == 0) row_ptr[n] = base;
}

// ---------------------------------------------------------------- CSR fill
__global__ __launch_bounds__(256) void fill_kernel(const int* __restrict__ src,
                                                   const int* __restrict__ dst,
                                                   const float* __restrict__ w,
                                                   int* __restrict__ nxt,
                                                   int* __restrict__ esrc,
                                                   float* __restrict__ ew) {
    int i = blockIdx.x * blockDim.x + threadIdx.x;
    if (i < NE) {
        int p = atomicAdd(&nxt[dst[i]], 1);
        esrc[p] = src[i];
        ew[p] = w[i];
    }
}

// ---------------------------------------------------------------- fp32 GEMM
// C[M,BN] = A[M,K] @ B[K,BN].  One block-column (BN == full N).
template <int BM, int BN, int BK, int TM, int TN>
__global__ __launch_bounds__((BM / TM) * (BN / TN)) void gemm_kernel(
    const float* __restrict__ A, const float* __restrict__ B,
    float* __restrict__ C, int M, int K) {
    constexpr int TX = BN / TN;
    constexpr int TY = BM / TM;
    constexpr int NT = TX * TY;
    __shared__ float As[BM][BK + 4];   // +4 keeps 16B alignment, breaks conflicts
    __shared__ float Bs[BK][BN];

    const int tid = threadIdx.x;
    const int tx = tid % TX;
    const int ty = tid / TX;
    const int row0 = blockIdx.x * BM;

    float acc[TM][TN] = {};

    for (int k0 = 0; k0 < K; k0 += BK) {
        #pragma unroll
        for (int i = tid; i < BM * BK / 4; i += NT) {
            int m = i / (BK / 4);
            int kv = i % (BK / 4);
            int gm = row0 + m;
            if (gm >= M) gm = M - 1;
            float4 v = *(const float4*)(A + (size_t)gm * K + k0 + kv * 4);
            As[m][kv * 4 + 0] = v.x;
            As[m][kv * 4 + 1] = v.y;
            As[m][kv * 4 + 2] = v.z;
            As[m][kv * 4 + 3] = v.w;
        }
        #pragma unroll
        for (int i = tid; i < BK * BN / 4; i += NT) {
            int kk = i / (BN / 4);
            int nv = i % (BN / 4);
            *(float4*)&Bs[kk][nv * 4] =
                *(const float4*)(B + (size_t)(k0 + kk) * BN + nv * 4);
        }
        __syncthreads();
        #pragma unroll
        for (int kk = 0; kk < BK; ++kk) {
            float a[TM], b[TN];
            #pragma unroll
            for (int i = 0; i < TM; ++i) a[i] = As[ty * TM + i][kk];
            #pragma unroll
            for (int j = 0; j < TN; ++j) b[j] = Bs[kk][tx * TN + j];
            #pragma unroll
            for (int i = 0; i < TM; ++i)
                #pragma unroll
                for (int j = 0; j < TN; ++j) acc[i][j] += a[i] * b[j];
        }
        __syncthreads();
    }
    #pragma unroll
    for (int i = 0; i < TM; ++i) {
        int gm = row0 + ty * TM + i;
        if (gm < M) {
            #pragma unroll
            for (int j = 0; j < TN; ++j)
                C[(size_t)gm * BN + tx * TN + j] = acc[i][j];
        }
    }
}

// ---------------------------------------------------------------- propagation
// out[n][:] = reduce_{e in CSR row n} ew[e] * x[esrc[e]][:]  (+ epilogue)
// MODE 0: out = acc + bias[d]           (extra = bias, length D)
// MODE 1: out = 0.9*acc + 0.1*h[n][d]   (extra = h, length NN*D)
template <int D, int MODE>
__global__ __launch_bounds__(256) void prop_kernel(
    const int* __restrict__ row_ptr, const int* __restrict__ esrc,
    const float* __restrict__ ew, const float* __restrict__ x,
    const float* __restrict__ extra, float* __restrict__ out) {
    constexpr int TPN = D / 4;        // threads per node (float4 each)
    constexpr int NPB = 256 / TPN;    // nodes per block
    const int local = threadIdx.x / TPN;
    const int lane = threadIdx.x % TPN;
    const int n = blockIdx.x * NPB + local;
    if (n >= NN) return;

    const int beg = row_ptr[n];
    const int end = row_ptr[n + 1];

    float ax = 0.f, ay = 0.f, az = 0.f, aw = 0.f;
    int e = beg;
    // 2-way unroll for ILP (two independent gather chains in flight)
    for (; e + 1 < end; e += 2) {
        int s0 = esrc[e];
        int s1 = esrc[e + 1];
        float w0 = ew[e];
        float w1 = ew[e + 1];
        float4 v0 = *(const float4*)(x + (size_t)s0 * D + lane * 4);
        float4 v1 = *(const float4*)(x + (size_t)s1 * D + lane * 4);
        ax += w0 * v0.x; ay += w0 * v0.y; az += w0 * v0.z; aw += w0 * v0.w;
        ax += w1 * v1.x; ay += w1 * v1.y; az += w1 * v1.z; aw += w1 * v1.w;
    }
    if (e < end) {
        int s0 = esrc[e];
        float w0 = ew[e];
        float4 v0 = *(const float4*)(x + (size_t)s0 * D + lane * 4);
        ax += w0 * v0.x; ay += w0 * v0.y; az += w0 * v0.z; aw += w0 * v0.w;
    }

    float4 r;
    if (MODE == 0) {
        float4 b = *(const float4*)(extra + lane * 4);
        r.x = ax + b.x; r.y = ay + b.y; r.z = az + b.z; r.w = aw + b.w;
    } else {
        float4 hh = *(const float4*)(extra + (size_t)n * D + lane * 4);
        r.x = 0.9f * ax + 0.1f * hh.x;
        r.y = 0.9f * ay + 0.1f * hh.y;
        r.z = 0.9f * az + 0.1f * hh.z;
        r.w = 0.9f * aw + 0.1f * hh.w;
    }
    *(float4*)(out + (size_t)n * D + lane * 4) = r;
}

__global__ void write_scalar_kernel(float* p, float v) { *p = v; }

// ---------------------------------------------------------------- launch
extern "C" void kernel_launch(void* const* d_in, const int* in_sizes, int n_in,
                              void* d_out, int out_size, void* d_ws, size_t ws_size,
                              hipStream_t stream) {
    const float* features = (const float*)d_in[0];
    const int* edge_index = (const int*)d_in[1];
    const float* edge_w = (const float*)d_in[2];
    const float* W1 = (const float*)d_in[3];
    const float* b1 = (const float*)d_in[4];
    const float* W2 = (const float*)d_in[5];
    const float* b2 = (const float*)d_in[6];
    const int* src = edge_index;        // edge_index[0]
    const int* dst = edge_index + NE;   // edge_index[1]

    // workspace carve-out (all 256B aligned); total ~71 MB
    char* ws = (char*)d_ws;
    auto carve = [&](size_t bytes) {
        char* p = ws;
        ws += (bytes + 255) & ~(size_t)255;
        return p;
    };
    int* cnt = (int*)carve((size_t)NN * 4);
    int* nxt = (int*)carve((size_t)NN * 4);
    int* row_ptr = (int*)carve((size_t)(NN + 1) * 4);
    int* esrc = (int*)carve((size_t)NE * 4);
    float* ew = (float*)carve((size_t)NE * 4);
    float* bufA = (float*)carve((size_t)NN * 128 * 4);
    float* bufB = (float*)carve((size_t)NN * 128 * 4);
    float* h = (float*)carve((size_t)NN * 64 * 4);

    const int EB = (NE + 255) / 256;

    // ---- CSR build (by destination) ----
    hipMemsetAsync(cnt, 0, (size_t)NN * 4, stream);
    hist_kernel<<<EB, 256, 0, stream>>>(dst, cnt);
    scan_kernel<<<1, 1024, 0, stream>>>(cnt, row_ptr, nxt, NN);
    fill_kernel<<<EB, 256, 0, stream>>>(src, dst, edge_w, nxt, esrc, ew);

    // ---- conv1: x1 = prop(features @ W1) + b1   [NN,128] ----
    gemm_kernel<64, 128, 32, 8, 4>
        <<<(NN + 63) / 64, 256, 0, stream>>>(features, W1, bufA, NN, 256);
    prop_kernel<128, 0>
        <<<(NN + 7) / 8, 256, 0, stream>>>(row_ptr, esrc, ew, bufA, b1, bufB);

    // ---- conv2: h = prop(x1 @ W2) + b2   [NN,64] ----
    gemm_kernel<128, 64, 32, 8, 4>
        <<<(NN + 127) / 128, 256, 0, stream>>>(bufB, W2, bufA, NN, 128);
    prop_kernel<64, 0>
        <<<(NN + 15) / 16, 256, 0, stream>>>(row_ptr, esrc, ew, bufA, b2, h);

    // ---- APPNP: 10 steps of x = 0.9*prop(x) + 0.1*h ----
    const float* x_cur = h;
    for (int k = 0; k < 10; ++k) {
        float* out = (k == 9) ? (float*)d_out : ((k & 1) ? bufB : bufA);
        prop_kernel<64, 1>
            <<<(NN + 15) / 16, 256, 0, stream>>>(row_ptr, esrc, ew, x_cur, h, out);
        x_cur = out;
    }

    // ---- second tuple element: the Python int 10 ----
    if (out_size > NN * 64) {
        write_scalar_kernel<<<1, 1, 0, stream>>>((float*)d_out + (size_t)NN * 64,
                                                 10.0f);
    }
}

// Round 2
// 608.323 us; speedup vs baseline: 1.1371x; 1.1371x over previous
//
#include <hip/hip_runtime.h>

#define NN 50000
#define NE 800000
#define SCAN_NB ((NN + 255) / 256)

// ------------------------------------------------ hist + per-edge rank
__global__ __launch_bounds__(256) void hist_rank_kernel(const int* __restrict__ dst,
                                                        int* __restrict__ cnt,
                                                        int* __restrict__ rank) {
    int i = blockIdx.x * blockDim.x + threadIdx.x;
    if (i < NE) rank[i] = atomicAdd(&cnt[dst[i]], 1);
}

// ------------------------------------------------ 3-kernel parallel scan
__global__ __launch_bounds__(256) void scan_block_kernel(const int* __restrict__ cnt,
                                                         int* __restrict__ row_ptr,
                                                         int* __restrict__ partial,
                                                         int n) {
    __shared__ int wsums[4];
    int i = blockIdx.x * 256 + threadIdx.x;
    int v = (i < n) ? cnt[i] : 0;
    const int lane = threadIdx.x & 63;
    const int wid = threadIdx.x >> 6;
    int incl = v;
    #pragma unroll
    for (int off = 1; off < 64; off <<= 1) {
        int t = __shfl_up(incl, off);
        if (lane >= off) incl += t;
    }
    if (lane == 63) wsums[wid] = incl;
    __syncthreads();
    int woff = 0;
    #pragma unroll
    for (int w = 0; w < 4; ++w)
        if (w < wid) woff += wsums[w];
    if (i < n) row_ptr[i] = woff + incl - v;   // intra-block exclusive
    if (threadIdx.x == 0)
        partial[blockIdx.x] = wsums[0] + wsums[1] + wsums[2] + wsums[3];
}

__global__ __launch_bounds__(256) void scan_partials_kernel(int* __restrict__ partial,
                                                            int* __restrict__ pexcl,
                                                            int* __restrict__ row_ptr,
                                                            int np) {
    __shared__ int wsums[4];
    int v = (threadIdx.x < np) ? partial[threadIdx.x] : 0;
    const int lane = threadIdx.x & 63;
    const int wid = threadIdx.x >> 6;
    int incl = v;
    #pragma unroll
    for (int off = 1; off < 64; off <<= 1) {
        int t = __shfl_up(incl, off);
        if (lane >= off) incl += t;
    }
    if (lane == 63) wsums[wid] = incl;
    __syncthreads();
    int woff = 0;
    #pragma unroll
    for (int w = 0; w < 4; ++w)
        if (w < wid) woff += wsums[w];
    if (threadIdx.x < np) pexcl[threadIdx.x] = woff + incl - v;
    if (threadIdx.x == 0) row_ptr[NN] = NE;
}

__global__ __launch_bounds__(256) void scan_add_kernel(int* __restrict__ row_ptr,
                                                       const int* __restrict__ pexcl,
                                                       int n) {
    int i = blockIdx.x * 256 + threadIdx.x;
    if (i < n) row_ptr[i] += pexcl[blockIdx.x];
}

// ------------------------------------------------ CSR fill (atomic-free)
__global__ __launch_bounds__(256) void fill_kernel(const int* __restrict__ src,
                                                   const int* __restrict__ dst,
                                                   const float* __restrict__ w,
                                                   const int* __restrict__ row_ptr,
                                                   const int* __restrict__ rank,
                                                   int2* __restrict__ er) {
    int i = blockIdx.x * blockDim.x + threadIdx.x;
    if (i < NE) {
        int p = row_ptr[dst[i]] + rank[i];
        er[p] = make_int2(src[i], __float_as_int(w[i]));
    }
}

// ------------------------------------------------ fp32 GEMM (TN must be 4)
template <int BM, int BN, int BK, int TM, int TN>
__global__ __launch_bounds__((BM / TM) * (BN / TN)) void gemm_kernel(
    const float* __restrict__ A, const float* __restrict__ B,
    float* __restrict__ C, int M, int K) {
    static_assert(TN == 4, "TN must be 4");
    constexpr int TX = BN / TN;
    constexpr int TY = BM / TM;
    constexpr int NT = TX * TY;
    __shared__ float As[BM][BK + 4];
    __shared__ float Bs[BK][BN];

    const int tid = threadIdx.x;
    const int tx = tid % TX;
    const int ty = tid / TX;
    const int row0 = blockIdx.x * BM;

    float4 acc[TM];
    #pragma unroll
    for (int i = 0; i < TM; ++i) acc[i] = make_float4(0.f, 0.f, 0.f, 0.f);

    for (int k0 = 0; k0 < K; k0 += BK) {
        #pragma unroll
        for (int i = tid; i < BM * BK / 4; i += NT) {
            int m = i / (BK / 4);
            int kv = i % (BK / 4);
            int gm = row0 + m;
            if (gm >= M) gm = M - 1;
            float4 v = *(const float4*)(A + (size_t)gm * K + k0 + kv * 4);
            As[m][kv * 4 + 0] = v.x;
            As[m][kv * 4 + 1] = v.y;
            As[m][kv * 4 + 2] = v.z;
            As[m][kv * 4 + 3] = v.w;
        }
        #pragma unroll
        for (int i = tid; i < BK * BN / 4; i += NT) {
            int kk = i / (BN / 4);
            int nv = i % (BN / 4);
            *(float4*)&Bs[kk][nv * 4] =
                *(const float4*)(B + (size_t)(k0 + kk) * BN + nv * 4);
        }
        __syncthreads();
        #pragma unroll
        for (int kk = 0; kk < BK; ++kk) {
            float4 b = *(const float4*)&Bs[kk][tx * 4];
            float a[TM];
            #pragma unroll
            for (int i = 0; i < TM; ++i) a[i] = As[ty * TM + i][kk];
            #pragma unroll
            for (int i = 0; i < TM; ++i) {
                acc[i].x += a[i] * b.x;
                acc[i].y += a[i] * b.y;
                acc[i].z += a[i] * b.z;
                acc[i].w += a[i] * b.w;
            }
        }
        __syncthreads();
    }
    #pragma unroll
    for (int i = 0; i < TM; ++i) {
        int gm = row0 + ty * TM + i;
        if (gm < M) *(float4*)(C + (size_t)gm * BN + tx * 4) = acc[i];
    }
}

// ------------------------------------------------ propagation
// MODE 0: out = acc + bias[d]         (extra = bias, length D)
// MODE 1: out = 0.9*acc + 0.1*h[n][d] (extra = h, length NN*D)
template <int D, int MODE>
__global__ __launch_bounds__(256) void prop_kernel(
    const int* __restrict__ row_ptr, const int2* __restrict__ er,
    const float* __restrict__ x, const float* __restrict__ extra,
    float* __restrict__ out) {
    constexpr int TPN = D / 4;
    constexpr int NPB = 256 / TPN;
    const int local = threadIdx.x / TPN;
    const int lane = threadIdx.x % TPN;
    const int n = blockIdx.x * NPB + local;
    if (n >= NN) return;

    int e = row_ptr[n];
    const int end = row_ptr[n + 1];

    float ax = 0.f, ay = 0.f, az = 0.f, aw = 0.f;
    for (; e + 3 < end; e += 4) {
        int2 r0 = er[e], r1 = er[e + 1], r2 = er[e + 2], r3 = er[e + 3];
        const float4 v0 = *(const float4*)(x + (size_t)r0.x * D + lane * 4);
        const float4 v1 = *(const float4*)(x + (size_t)r1.x * D + lane * 4);
        const float4 v2 = *(const float4*)(x + (size_t)r2.x * D + lane * 4);
        const float4 v3 = *(const float4*)(x + (size_t)r3.x * D + lane * 4);
        float w0 = __int_as_float(r0.y), w1 = __int_as_float(r1.y);
        float w2 = __int_as_float(r2.y), w3 = __int_as_float(r3.y);
        ax += w0 * v0.x; ay += w0 * v0.y; az += w0 * v0.z; aw += w0 * v0.w;
        ax += w1 * v1.x; ay += w1 * v1.y; az += w1 * v1.z; aw += w1 * v1.w;
        ax += w2 * v2.x; ay += w2 * v2.y; az += w2 * v2.z; aw += w2 * v2.w;
        ax += w3 * v3.x; ay += w3 * v3.y; az += w3 * v3.z; aw += w3 * v3.w;
    }
    for (; e < end; ++e) {
        int2 r0 = er[e];
        const float4 v0 = *(const float4*)(x + (size_t)r0.x * D + lane * 4);
        float w0 = __int_as_float(r0.y);
        ax += w0 * v0.x; ay += w0 * v0.y; az += w0 * v0.z; aw += w0 * v0.w;
    }

    float4 r;
    if (MODE == 0) {
        float4 b = *(const float4*)(extra + lane * 4);
        r.x = ax + b.x; r.y = ay + b.y; r.z = az + b.z; r.w = aw + b.w;
    } else {
        float4 hh = *(const float4*)(extra + (size_t)n * D + lane * 4);
        r.x = 0.9f * ax + 0.1f * hh.x;
        r.y = 0.9f * ay + 0.1f * hh.y;
        r.z = 0.9f * az + 0.1f * hh.z;
        r.w = 0.9f * aw + 0.1f * hh.w;
    }
    *(float4*)(out + (size_t)n * D + lane * 4) = r;
}

__global__ void write_scalar_kernel(float* p, float v) { *p = v; }

// ------------------------------------------------ launch
extern "C" void kernel_launch(void* const* d_in, const int* in_sizes, int n_in,
                              void* d_out, int out_size, void* d_ws, size_t ws_size,
                              hipStream_t stream) {
    const float* features = (const float*)d_in[0];
    const int* edge_index = (const int*)d_in[1];
    const float* edge_w = (const float*)d_in[2];
    const float* W1 = (const float*)d_in[3];
    const float* b1 = (const float*)d_in[4];
    const float* W2 = (const float*)d_in[5];
    const float* b2 = (const float*)d_in[6];
    const int* src = edge_index;        // edge_index[0]
    const int* dst = edge_index + NE;   // edge_index[1]

    char* ws = (char*)d_ws;
    auto carve = [&](size_t bytes) {
        char* p = ws;
        ws += (bytes + 255) & ~(size_t)255;
        return p;
    };
    int* cnt = (int*)carve((size_t)NN * 4);
    int* rank = (int*)carve((size_t)NE * 4);
    int* row_ptr = (int*)carve((size_t)(NN + 1) * 4);
    int* partial = (int*)carve((size_t)SCAN_NB * 4);
    int* pexcl = (int*)carve((size_t)SCAN_NB * 4);
    int2* erec = (int2*)carve((size_t)NE * 8);
    float* bufA = (float*)carve((size_t)NN * 128 * 4);
    float* bufB = (float*)carve((size_t)NN * 128 * 4);
    float* h = (float*)carve((size_t)NN * 64 * 4);

    const int EB = (NE + 255) / 256;

    // ---- CSR build (by destination) ----
    hipMemsetAsync(cnt, 0, (size_t)NN * 4, stream);
    hist_rank_kernel<<<EB, 256, 0, stream>>>(dst, cnt, rank);
    scan_block_kernel<<<SCAN_NB, 256, 0, stream>>>(cnt, row_ptr, partial, NN);
    scan_partials_kernel<<<1, 256, 0, stream>>>(partial, pexcl, row_ptr, SCAN_NB);
    scan_add_kernel<<<SCAN_NB, 256, 0, stream>>>(row_ptr, pexcl, NN);
    fill_kernel<<<EB, 256, 0, stream>>>(src, dst, edge_w, row_ptr, rank, erec);

    // ---- conv1: x1 = prop(features @ W1) + b1   [NN,128] ----
    gemm_kernel<32, 128, 16, 8, 4>
        <<<(NN + 31) / 32, 128, 0, stream>>>(features, W1, bufA, NN, 256);
    prop_kernel<128, 0>
        <<<(NN + 7) / 8, 256, 0, stream>>>(row_ptr, erec, bufA, b1, bufB);

    // ---- conv2: h = prop(x1 @ W2) + b2   [NN,64] ----
    gemm_kernel<32, 64, 16, 4, 4>
        <<<(NN + 31) / 32, 128, 0, stream>>>(bufB, W2, bufA, NN, 128);
    prop_kernel<64, 0>
        <<<(NN + 15) / 16, 256, 0, stream>>>(row_ptr, erec, bufA, b2, h);

    // ---- APPNP: 10 steps of x = 0.9*prop(x) + 0.1*h ----
    const float* x_cur = h;
    for (int k = 0; k < 10; ++k) {
        float* out = (k == 9) ? (float*)d_out : ((k & 1) ? bufB : bufA);
        prop_kernel<64, 1>
            <<<(NN + 15) / 16, 256, 0, stream>>>(row_ptr, erec, x_cur, h, out);
        x_cur = out;
    }

    // ---- second tuple element: the Python int 10 ----
    if (out_size > NN * 64) {
        write_scalar_kernel<<<1, 1, 0, stream>>>((float*)d_out + (size_t)NN * 64,
                                                 10.0f);
    }
}

// Round 3
// 440.184 us; speedup vs baseline: 1.5715x; 1.3820x over previous
//
#include <hip/hip_runtime.h>

#define NN 50000
#define NE 800000
#define SCAN_NB ((NN + 255) / 256)

// ------------------------------------------------ bf16 helpers (ushort = bf16)
__device__ inline void bf16x8_to_f32(const uint4 v, float* f) {
    f[0] = __uint_as_float(v.x << 16);
    f[1] = __uint_as_float(v.x & 0xffff0000u);
    f[2] = __uint_as_float(v.y << 16);
    f[3] = __uint_as_float(v.y & 0xffff0000u);
    f[4] = __uint_as_float(v.z << 16);
    f[5] = __uint_as_float(v.z & 0xffff0000u);
    f[6] = __uint_as_float(v.w << 16);
    f[7] = __uint_as_float(v.w & 0xffff0000u);
}

__device__ inline unsigned f32_to_bf16(float x) {  // RTNE
    unsigned u = __float_as_uint(x);
    return (u + 0x7fffu + ((u >> 16) & 1u)) >> 16;
}

__device__ inline uint4 f32x8_to_bf16(const float* f) {
    uint4 v;
    v.x = f32_to_bf16(f[0]) | (f32_to_bf16(f[1]) << 16);
    v.y = f32_to_bf16(f[2]) | (f32_to_bf16(f[3]) << 16);
    v.z = f32_to_bf16(f[4]) | (f32_to_bf16(f[5]) << 16);
    v.w = f32_to_bf16(f[6]) | (f32_to_bf16(f[7]) << 16);
    return v;
}

// ------------------------------------------------ hist + per-edge rank
__global__ __launch_bounds__(256) void hist_rank_kernel(const int* __restrict__ dst,
                                                        int* __restrict__ cnt,
                                                        int* __restrict__ rank) {
    int i = blockIdx.x * blockDim.x + threadIdx.x;
    if (i < NE) rank[i] = atomicAdd(&cnt[dst[i]], 1);
}

// ------------------------------------------------ 3-kernel parallel scan
__global__ __launch_bounds__(256) void scan_block_kernel(const int* __restrict__ cnt,
                                                         int* __restrict__ row_ptr,
                                                         int* __restrict__ partial,
                                                         int n) {
    __shared__ int wsums[4];
    int i = blockIdx.x * 256 + threadIdx.x;
    int v = (i < n) ? cnt[i] : 0;
    const int lane = threadIdx.x & 63;
    const int wid = threadIdx.x >> 6;
    int incl = v;
    #pragma unroll
    for (int off = 1; off < 64; off <<= 1) {
        int t = __shfl_up(incl, off);
        if (lane >= off) incl += t;
    }
    if (lane == 63) wsums[wid] = incl;
    __syncthreads();
    int woff = 0;
    #pragma unroll
    for (int w = 0; w < 4; ++w)
        if (w < wid) woff += wsums[w];
    if (i < n) row_ptr[i] = woff + incl - v;
    if (threadIdx.x == 0)
        partial[blockIdx.x] = wsums[0] + wsums[1] + wsums[2] + wsums[3];
}

__global__ __launch_bounds__(256) void scan_partials_kernel(int* __restrict__ partial,
                                                            int* __restrict__ pexcl,
                                                            int* __restrict__ row_ptr,
                                                            int np) {
    __shared__ int wsums[4];
    int v = (threadIdx.x < np) ? partial[threadIdx.x] : 0;
    const int lane = threadIdx.x & 63;
    const int wid = threadIdx.x >> 6;
    int incl = v;
    #pragma unroll
    for (int off = 1; off < 64; off <<= 1) {
        int t = __shfl_up(incl, off);
        if (lane >= off) incl += t;
    }
    if (lane == 63) wsums[wid] = incl;
    __syncthreads();
    int woff = 0;
    #pragma unroll
    for (int w = 0; w < 4; ++w)
        if (w < wid) woff += wsums[w];
    if (threadIdx.x < np) pexcl[threadIdx.x] = woff + incl - v;
    if (threadIdx.x == 0) row_ptr[NN] = NE;
}

__global__ __launch_bounds__(256) void scan_add_kernel(int* __restrict__ row_ptr,
                                                       const int* __restrict__ pexcl,
                                                       int n) {
    int i = blockIdx.x * 256 + threadIdx.x;
    if (i < n) row_ptr[i] += pexcl[blockIdx.x];
}

// ------------------------------------------------ CSR fill (atomic-free)
__global__ __launch_bounds__(256) void fill_kernel(const int* __restrict__ src,
                                                   const int* __restrict__ dst,
                                                   const float* __restrict__ w,
                                                   const int* __restrict__ row_ptr,
                                                   const int* __restrict__ rank,
                                                   int2* __restrict__ er) {
    int i = blockIdx.x * blockDim.x + threadIdx.x;
    if (i < NE) {
        int p = row_ptr[dst[i]] + rank[i];
        er[p] = make_int2(src[i], __float_as_int(w[i]));
    }
}

// ------------------------------------------------ fp32 GEMM, optional bf16 out
template <int BM, int BN, int BK, int TM, int TN, bool OUT_BF16>
__global__ __launch_bounds__((BM / TM) * (BN / TN)) void gemm_kernel(
    const float* __restrict__ A, const float* __restrict__ B,
    void* __restrict__ Cv, int M, int K) {
    static_assert(TN == 4, "TN must be 4");
    constexpr int TX = BN / TN;
    constexpr int TY = BM / TM;
    constexpr int NT = TX * TY;
    __shared__ float As[BM][BK + 4];
    __shared__ float Bs[BK][BN];

    const int tid = threadIdx.x;
    const int tx = tid % TX;
    const int ty = tid / TX;
    const int row0 = blockIdx.x * BM;

    float4 acc[TM];
    #pragma unroll
    for (int i = 0; i < TM; ++i) acc[i] = make_float4(0.f, 0.f, 0.f, 0.f);

    for (int k0 = 0; k0 < K; k0 += BK) {
        #pragma unroll
        for (int i = tid; i < BM * BK / 4; i += NT) {
            int m = i / (BK / 4);
            int kv = i % (BK / 4);
            int gm = row0 + m;
            if (gm >= M) gm = M - 1;
            float4 v = *(const float4*)(A + (size_t)gm * K + k0 + kv * 4);
            As[m][kv * 4 + 0] = v.x;
            As[m][kv * 4 + 1] = v.y;
            As[m][kv * 4 + 2] = v.z;
            As[m][kv * 4 + 3] = v.w;
        }
        #pragma unroll
        for (int i = tid; i < BK * BN / 4; i += NT) {
            int kk = i / (BN / 4);
            int nv = i % (BN / 4);
            *(float4*)&Bs[kk][nv * 4] =
                *(const float4*)(B + (size_t)(k0 + kk) * BN + nv * 4);
        }
        __syncthreads();
        #pragma unroll
        for (int kk = 0; kk < BK; ++kk) {
            float4 b = *(const float4*)&Bs[kk][tx * 4];
            float a[TM];
            #pragma unroll
            for (int i = 0; i < TM; ++i) a[i] = As[ty * TM + i][kk];
            #pragma unroll
            for (int i = 0; i < TM; ++i) {
                acc[i].x += a[i] * b.x;
                acc[i].y += a[i] * b.y;
                acc[i].z += a[i] * b.z;
                acc[i].w += a[i] * b.w;
            }
        }
        __syncthreads();
    }
    #pragma unroll
    for (int i = 0; i < TM; ++i) {
        int gm = row0 + ty * TM + i;
        if (gm < M) {
            if (OUT_BF16) {
                ushort4 o;
                o.x = (unsigned short)f32_to_bf16(acc[i].x);
                o.y = (unsigned short)f32_to_bf16(acc[i].y);
                o.z = (unsigned short)f32_to_bf16(acc[i].z);
                o.w = (unsigned short)f32_to_bf16(acc[i].w);
                *(ushort4*)((unsigned short*)Cv + (size_t)gm * BN + tx * 4) = o;
            } else {
                *(float4*)((float*)Cv + (size_t)gm * BN + tx * 4) = acc[i];
            }
        }
    }
}

// ------------------------------------------------ propagation (bf16 gathers)
// out[n][:] = reduce ew[e] * x_bf16[esrc[e]][:]  (+ epilogue)
// MODE 0: out = acc + bias[d]                (bias fp32[D])
// MODE 1: out = 0.9*acc + 0.1*h_bf16[n][d]
template <int D, int MODE, bool OUT_BF16>
__global__ __launch_bounds__(256) void prop_kernel(
    const int* __restrict__ row_ptr, const int2* __restrict__ er,
    const unsigned short* __restrict__ x, const float* __restrict__ bias,
    const unsigned short* __restrict__ hbf, void* __restrict__ outv) {
    constexpr int TPN = D / 8;        // threads per node, 8 bf16 (16B) each
    constexpr int NPB = 256 / TPN;
    const int local = threadIdx.x / TPN;
    const int lane = threadIdx.x % TPN;
    const int n = blockIdx.x * NPB + local;
    if (n >= NN) return;

    int e = row_ptr[n];
    const int end = row_ptr[n + 1];

    float acc[8] = {};
    for (; e + 3 < end; e += 4) {
        int2 r0 = er[e], r1 = er[e + 1], r2 = er[e + 2], r3 = er[e + 3];
        uint4 u0 = *(const uint4*)(x + (size_t)r0.x * D + lane * 8);
        uint4 u1 = *(const uint4*)(x + (size_t)r1.x * D + lane * 8);
        uint4 u2 = *(const uint4*)(x + (size_t)r2.x * D + lane * 8);
        uint4 u3 = *(const uint4*)(x + (size_t)r3.x * D + lane * 8);
        float w0 = __int_as_float(r0.y), w1 = __int_as_float(r1.y);
        float w2 = __int_as_float(r2.y), w3 = __int_as_float(r3.y);
        float f0[8], f1[8], f2[8], f3[8];
        bf16x8_to_f32(u0, f0);
        bf16x8_to_f32(u1, f1);
        bf16x8_to_f32(u2, f2);
        bf16x8_to_f32(u3, f3);
        #pragma unroll
        for (int j = 0; j < 8; ++j) {
            acc[j] += w0 * f0[j];
            acc[j] += w1 * f1[j];
            acc[j] += w2 * f2[j];
            acc[j] += w3 * f3[j];
        }
    }
    for (; e < end; ++e) {
        int2 r0 = er[e];
        uint4 u0 = *(const uint4*)(x + (size_t)r0.x * D + lane * 8);
        float w0 = __int_as_float(r0.y);
        float f0[8];
        bf16x8_to_f32(u0, f0);
        #pragma unroll
        for (int j = 0; j < 8; ++j) acc[j] += w0 * f0[j];
    }

    float r[8];
    if (MODE == 0) {
        #pragma unroll
        for (int j = 0; j < 8; ++j) r[j] = acc[j] + bias[lane * 8 + j];
    } else {
        uint4 uh = *(const uint4*)(hbf + (size_t)n * D + lane * 8);
        float fh[8];
        bf16x8_to_f32(uh, fh);
        #pragma unroll
        for (int j = 0; j < 8; ++j) r[j] = 0.9f * acc[j] + 0.1f * fh[j];
    }

    if (OUT_BF16) {
        *(uint4*)((unsigned short*)outv + (size_t)n * D + lane * 8) =
            f32x8_to_bf16(r);
    } else {
        float* o = (float*)outv + (size_t)n * D + lane * 8;
        *(float4*)(o + 0) = make_float4(r[0], r[1], r[2], r[3]);
        *(float4*)(o + 4) = make_float4(r[4], r[5], r[6], r[7]);
    }
}

__global__ void write_scalar_kernel(float* p, float v) { *p = v; }

// ------------------------------------------------ launch
extern "C" void kernel_launch(void* const* d_in, const int* in_sizes, int n_in,
                              void* d_out, int out_size, void* d_ws, size_t ws_size,
                              hipStream_t stream) {
    const float* features = (const float*)d_in[0];
    const int* edge_index = (const int*)d_in[1];
    const float* edge_w = (const float*)d_in[2];
    const float* W1 = (const float*)d_in[3];
    const float* b1 = (const float*)d_in[4];
    const float* W2 = (const float*)d_in[5];
    const float* b2 = (const float*)d_in[6];
    const int* src = edge_index;        // edge_index[0]
    const int* dst = edge_index + NE;   // edge_index[1]

    char* ws = (char*)d_ws;
    auto carve = [&](size_t bytes) {
        char* p = ws;
        ws += (bytes + 255) & ~(size_t)255;
        return p;
    };
    int* cnt = (int*)carve((size_t)NN * 4);
    int* rank = (int*)carve((size_t)NE * 4);
    int* row_ptr = (int*)carve((size_t)(NN + 1) * 4);
    int* partial = (int*)carve((size_t)SCAN_NB * 4);
    int* pexcl = (int*)carve((size_t)SCAN_NB * 4);
    int2* erec = (int2*)carve((size_t)NE * 8);
    unsigned short* y1_bf = (unsigned short*)carve((size_t)NN * 128 * 2);
    float* x1_f32 = (float*)carve((size_t)NN * 128 * 4);
    unsigned short* y2_bf = (unsigned short*)carve((size_t)NN * 64 * 2);
    unsigned short* h_bf = (unsigned short*)carve((size_t)NN * 64 * 2);
    unsigned short* xb0 = (unsigned short*)carve((size_t)NN * 64 * 2);
    unsigned short* xb1 = (unsigned short*)carve((size_t)NN * 64 * 2);

    const int EB = (NE + 255) / 256;

    // ---- CSR build (by destination) ----
    hipMemsetAsync(cnt, 0, (size_t)NN * 4, stream);
    hist_rank_kernel<<<EB, 256, 0, stream>>>(dst, cnt, rank);
    scan_block_kernel<<<SCAN_NB, 256, 0, stream>>>(cnt, row_ptr, partial, NN);
    scan_partials_kernel<<<1, 256, 0, stream>>>(partial, pexcl, row_ptr, SCAN_NB);
    scan_add_kernel<<<SCAN_NB, 256, 0, stream>>>(row_ptr, pexcl, NN);
    fill_kernel<<<EB, 256, 0, stream>>>(src, dst, edge_w, row_ptr, rank, erec);

    // ---- conv1: x1 = prop(features @ W1) + b1 ----
    gemm_kernel<64, 128, 32, 8, 4, true>
        <<<(NN + 63) / 64, 256, 0, stream>>>(features, W1, y1_bf, NN, 256);
    prop_kernel<128, 0, false>
        <<<(NN * 16 + 255) / 256, 256, 0, stream>>>(row_ptr, erec, y1_bf, b1,
                                                    nullptr, x1_f32);

    // ---- conv2: h = prop(x1 @ W2) + b2 ----
    gemm_kernel<128, 64, 32, 8, 4, true>
        <<<(NN + 127) / 128, 256, 0, stream>>>(x1_f32, W2, y2_bf, NN, 128);
    prop_kernel<64, 0, true>
        <<<(NN * 8 + 255) / 256, 256, 0, stream>>>(row_ptr, erec, y2_bf, b2,
                                                   nullptr, h_bf);

    // ---- APPNP: 10 steps of x = 0.9*prop(x) + 0.1*h ----
    const unsigned short* x_cur = h_bf;
    for (int k = 0; k < 9; ++k) {
        unsigned short* out = (k & 1) ? xb1 : xb0;
        prop_kernel<64, 1, true>
            <<<(NN * 8 + 255) / 256, 256, 0, stream>>>(row_ptr, erec, x_cur,
                                                       nullptr, h_bf, out);
        x_cur = out;
    }
    prop_kernel<64, 1, false>
        <<<(NN * 8 + 255) / 256, 256, 0, stream>>>(row_ptr, erec, x_cur, nullptr,
                                                   h_bf, (float*)d_out);

    // ---- second tuple element: the Python int 10 ----
    if (out_size > NN * 64) {
        write_scalar_kernel<<<1, 1, 0, stream>>>((float*)d_out + (size_t)NN * 64,
                                                 10.0f);
    }
}

// Round 4
// 395.966 us; speedup vs baseline: 1.7470x; 1.1117x over previous
//
#include <hip/hip_runtime.h>

#define NN 50000
#define NE 800000
#define SCAN_NB ((NN + 255) / 256)

typedef short bf16x8 __attribute__((ext_vector_type(8)));
typedef float f32x4 __attribute__((ext_vector_type(4)));

// ------------------------------------------------ bf16 helpers (ushort = bf16)
__device__ inline void bf16x8_to_f32(const uint4 v, float* f) {
    f[0] = __uint_as_float(v.x << 16);
    f[1] = __uint_as_float(v.x & 0xffff0000u);
    f[2] = __uint_as_float(v.y << 16);
    f[3] = __uint_as_float(v.y & 0xffff0000u);
    f[4] = __uint_as_float(v.z << 16);
    f[5] = __uint_as_float(v.z & 0xffff0000u);
    f[6] = __uint_as_float(v.w << 16);
    f[7] = __uint_as_float(v.w & 0xffff0000u);
}

__device__ inline unsigned f32_to_bf16(float x) {  // RTNE
    unsigned u = __float_as_uint(x);
    return (u + 0x7fffu + ((u >> 16) & 1u)) >> 16;
}

__device__ inline uint4 f32x8_to_bf16(const float* f) {
    uint4 v;
    v.x = f32_to_bf16(f[0]) | (f32_to_bf16(f[1]) << 16);
    v.y = f32_to_bf16(f[2]) | (f32_to_bf16(f[3]) << 16);
    v.z = f32_to_bf16(f[4]) | (f32_to_bf16(f[5]) << 16);
    v.w = f32_to_bf16(f[6]) | (f32_to_bf16(f[7]) << 16);
    return v;
}

// ------------------------------------------------ hist + per-edge rank
__global__ __launch_bounds__(256) void hist_rank_kernel(const int* __restrict__ dst,
                                                        int* __restrict__ cnt,
                                                        int* __restrict__ rank) {
    int i = blockIdx.x * blockDim.x + threadIdx.x;
    if (i < NE) rank[i] = atomicAdd(&cnt[dst[i]], 1);
}

// ------------------------------------------------ 3-kernel parallel scan
__global__ __launch_bounds__(256) void scan_block_kernel(const int* __restrict__ cnt,
                                                         int* __restrict__ row_ptr,
                                                         int* __restrict__ partial,
                                                         int n) {
    __shared__ int wsums[4];
    int i = blockIdx.x * 256 + threadIdx.x;
    int v = (i < n) ? cnt[i] : 0;
    const int lane = threadIdx.x & 63;
    const int wid = threadIdx.x >> 6;
    int incl = v;
    #pragma unroll
    for (int off = 1; off < 64; off <<= 1) {
        int t = __shfl_up(incl, off);
        if (lane >= off) incl += t;
    }
    if (lane == 63) wsums[wid] = incl;
    __syncthreads();
    int woff = 0;
    #pragma unroll
    for (int w = 0; w < 4; ++w)
        if (w < wid) woff += wsums[w];
    if (i < n) row_ptr[i] = woff + incl - v;
    if (threadIdx.x == 0)
        partial[blockIdx.x] = wsums[0] + wsums[1] + wsums[2] + wsums[3];
}

__global__ __launch_bounds__(256) void scan_partials_kernel(int* __restrict__ partial,
                                                            int* __restrict__ pexcl,
                                                            int* __restrict__ row_ptr,
                                                            int np) {
    __shared__ int wsums[4];
    int v = (threadIdx.x < np) ? partial[threadIdx.x] : 0;
    const int lane = threadIdx.x & 63;
    const int wid = threadIdx.x >> 6;
    int incl = v;
    #pragma unroll
    for (int off = 1; off < 64; off <<= 1) {
        int t = __shfl_up(incl, off);
        if (lane >= off) incl += t;
    }
    if (lane == 63) wsums[wid] = incl;
    __syncthreads();
    int woff = 0;
    #pragma unroll
    for (int w = 0; w < 4; ++w)
        if (w < wid) woff += wsums[w];
    if (threadIdx.x < np) pexcl[threadIdx.x] = woff + incl - v;
    if (threadIdx.x == 0) row_ptr[NN] = NE;
}

__global__ __launch_bounds__(256) void scan_add_kernel(int* __restrict__ row_ptr,
                                                       const int* __restrict__ pexcl,
                                                       int n) {
    int i = blockIdx.x * 256 + threadIdx.x;
    if (i < n) row_ptr[i] += pexcl[blockIdx.x];
}

// ------------------------------------------------ CSR fill (atomic-free)
__global__ __launch_bounds__(256) void fill_kernel(const int* __restrict__ src,
                                                   const int* __restrict__ dst,
                                                   const float* __restrict__ w,
                                                   const int* __restrict__ row_ptr,
                                                   const int* __restrict__ rank,
                                                   int2* __restrict__ er) {
    int i = blockIdx.x * blockDim.x + threadIdx.x;
    if (i < NE) {
        int p = row_ptr[dst[i]] + rank[i];
        er[p] = make_int2(src[i], __float_as_int(w[i]));
    }
}

// ------------------------------------------------ W transpose: fp32[K][N] -> bf16[N][K]
__global__ __launch_bounds__(256) void wtrans_kernel(const float* __restrict__ W,
                                                     unsigned short* __restrict__ WT,
                                                     int K, int N) {
    int i = blockIdx.x * 256 + threadIdx.x;
    if (i < K * N) {
        int n = i / K, k = i % K;
        WT[i] = (unsigned short)f32_to_bf16(W[(size_t)k * N + n]);
    }
}

// ------------------------------------------------ MFMA bf16 GEMM
// A: fp32 or bf16 [M,K]; BT: bf16 [N,K] (pre-transposed); C: bf16 [M,N].
// BM=64, BK=32, 256 threads = 4 waves, wave w owns rows [w*16, w*16+16).
template <int N, int K, bool A_BF16>
__global__ __launch_bounds__(256) void gemm_mfma_kernel(
    const void* __restrict__ Av, const unsigned short* __restrict__ BT,
    unsigned short* __restrict__ C, int M) {
    constexpr int NT = N / 16;   // n-tiles per wave
    constexpr int KS = K / 32;   // k-steps
    __shared__ unsigned short As[64][40];   // stride 40: 2-way-max bank aliasing
    __shared__ unsigned short Bs[N][40];

    const int tid = threadIdx.x;
    const int wave = tid >> 6;
    const int lane = tid & 63;
    const int lm = lane & 15;      // m / n within tile
    const int lq = lane >> 4;      // k-quad
    const int row0 = blockIdx.x * 64;
    const int m0 = wave * 16;

    f32x4 acc[NT] = {};

    for (int ks = 0; ks < KS; ++ks) {
        const int k0 = ks * 32;
        // stage A tile 64x32 (convert fp32->bf16 if needed)
        {
            int m = tid >> 2, kc = (tid & 3) * 8;
            int gm = row0 + m;
            if (gm >= M) gm = M - 1;
            if (A_BF16) {
                const unsigned short* A = (const unsigned short*)Av;
                *(uint4*)&As[m][kc] = *(const uint4*)(A + (size_t)gm * K + k0 + kc);
            } else {
                const float* A = (const float*)Av;
                float4 v0 = *(const float4*)(A + (size_t)gm * K + k0 + kc);
                float4 v1 = *(const float4*)(A + (size_t)gm * K + k0 + kc + 4);
                float f[8] = {v0.x, v0.y, v0.z, v0.w, v1.x, v1.y, v1.z, v1.w};
                *(uint4*)&As[m][kc] = f32x8_to_bf16(f);
            }
        }
        // stage B tile Nx32 from BT (already bf16, [n][k] contiguous)
        #pragma unroll
        for (int c = tid; c < N * 4; c += 256) {
            int n = c >> 2, kc = (c & 3) * 8;
            *(uint4*)&Bs[n][kc] = *(const uint4*)(BT + (size_t)n * K + k0 + kc);
        }
        __syncthreads();
        bf16x8 a = *(const bf16x8*)&As[m0 + lm][lq * 8];
        #pragma unroll
        for (int t = 0; t < NT; ++t) {
            bf16x8 b = *(const bf16x8*)&Bs[t * 16 + lm][lq * 8];
            acc[t] = __builtin_amdgcn_mfma_f32_16x16x32_bf16(a, b, acc[t], 0, 0, 0);
        }
        __syncthreads();
    }
    // epilogue: C/D layout col=lane&15, row=quad*4+reg
    #pragma unroll
    for (int t = 0; t < NT; ++t) {
        #pragma unroll
        for (int r = 0; r < 4; ++r) {
            int gm = row0 + m0 + lq * 4 + r;
            if (gm < M)
                C[(size_t)gm * N + t * 16 + lm] =
                    (unsigned short)f32_to_bf16(acc[t][r]);
        }
    }
}

// ------------------------------------------------ propagation (bf16 gathers)
// MODE 0: out = acc + bias[d]   MODE 1: out = 0.9*acc + 0.1*h_bf16[n][d]
template <int D, int MODE, bool OUT_BF16>
__global__ __launch_bounds__(256) void prop_kernel(
    const int* __restrict__ row_ptr, const int2* __restrict__ er,
    const unsigned short* __restrict__ x, const float* __restrict__ bias,
    const unsigned short* __restrict__ hbf, void* __restrict__ outv) {
    constexpr int TPN = D / 8;
    constexpr int NPB = 256 / TPN;
    const int local = threadIdx.x / TPN;
    const int lane = threadIdx.x % TPN;
    const int n = blockIdx.x * NPB + local;
    if (n >= NN) return;

    int e = row_ptr[n];
    const int end = row_ptr[n + 1];

    float acc[8] = {};
    for (; e + 3 < end; e += 4) {
        int2 r0 = er[e], r1 = er[e + 1], r2 = er[e + 2], r3 = er[e + 3];
        uint4 u0 = *(const uint4*)(x + (size_t)r0.x * D + lane * 8);
        uint4 u1 = *(const uint4*)(x + (size_t)r1.x * D + lane * 8);
        uint4 u2 = *(const uint4*)(x + (size_t)r2.x * D + lane * 8);
        uint4 u3 = *(const uint4*)(x + (size_t)r3.x * D + lane * 8);
        float w0 = __int_as_float(r0.y), w1 = __int_as_float(r1.y);
        float w2 = __int_as_float(r2.y), w3 = __int_as_float(r3.y);
        float f0[8], f1[8], f2[8], f3[8];
        bf16x8_to_f32(u0, f0);
        bf16x8_to_f32(u1, f1);
        bf16x8_to_f32(u2, f2);
        bf16x8_to_f32(u3, f3);
        #pragma unroll
        for (int j = 0; j < 8; ++j) {
            acc[j] += w0 * f0[j];
            acc[j] += w1 * f1[j];
            acc[j] += w2 * f2[j];
            acc[j] += w3 * f3[j];
        }
    }
    for (; e < end; ++e) {
        int2 r0 = er[e];
        uint4 u0 = *(const uint4*)(x + (size_t)r0.x * D + lane * 8);
        float w0 = __int_as_float(r0.y);
        float f0[8];
        bf16x8_to_f32(u0, f0);
        #pragma unroll
        for (int j = 0; j < 8; ++j) acc[j] += w0 * f0[j];
    }

    float r[8];
    if (MODE == 0) {
        #pragma unroll
        for (int j = 0; j < 8; ++j) r[j] = acc[j] + bias[lane * 8 + j];
    } else {
        uint4 uh = *(const uint4*)(hbf + (size_t)n * D + lane * 8);
        float fh[8];
        bf16x8_to_f32(uh, fh);
        #pragma unroll
        for (int j = 0; j < 8; ++j) r[j] = 0.9f * acc[j] + 0.1f * fh[j];
    }

    if (OUT_BF16) {
        *(uint4*)((unsigned short*)outv + (size_t)n * D + lane * 8) =
            f32x8_to_bf16(r);
    } else {
        float* o = (float*)outv + (size_t)n * D + lane * 8;
        *(float4*)(o + 0) = make_float4(r[0], r[1], r[2], r[3]);
        *(float4*)(o + 4) = make_float4(r[4], r[5], r[6], r[7]);
    }
}

__global__ void write_scalar_kernel(float* p, float v) { *p = v; }

// ------------------------------------------------ launch
extern "C" void kernel_launch(void* const* d_in, const int* in_sizes, int n_in,
                              void* d_out, int out_size, void* d_ws, size_t ws_size,
                              hipStream_t stream) {
    const float* features = (const float*)d_in[0];
    const int* edge_index = (const int*)d_in[1];
    const float* edge_w = (const float*)d_in[2];
    const float* W1 = (const float*)d_in[3];
    const float* b1 = (const float*)d_in[4];
    const float* W2 = (const float*)d_in[5];
    const float* b2 = (const float*)d_in[6];
    const int* src = edge_index;        // edge_index[0]
    const int* dst = edge_index + NE;   // edge_index[1]

    char* ws = (char*)d_ws;
    auto carve = [&](size_t bytes) {
        char* p = ws;
        ws += (bytes + 255) & ~(size_t)255;
        return p;
    };
    int* cnt = (int*)carve((size_t)NN * 4);
    int* rank = (int*)carve((size_t)NE * 4);
    int* row_ptr = (int*)carve((size_t)(NN + 1) * 4);
    int* partial = (int*)carve((size_t)SCAN_NB * 4);
    int* pexcl = (int*)carve((size_t)SCAN_NB * 4);
    int2* erec = (int2*)carve((size_t)NE * 8);
    unsigned short* W1T = (unsigned short*)carve((size_t)128 * 256 * 2);
    unsigned short* W2T = (unsigned short*)carve((size_t)64 * 128 * 2);
    unsigned short* y1_bf = (unsigned short*)carve((size_t)NN * 128 * 2);
    unsigned short* x1_bf = (unsigned short*)carve((size_t)NN * 128 * 2);
    unsigned short* y2_bf = (unsigned short*)carve((size_t)NN * 64 * 2);
    unsigned short* h_bf = (unsigned short*)carve((size_t)NN * 64 * 2);
    unsigned short* xb0 = (unsigned short*)carve((size_t)NN * 64 * 2);
    unsigned short* xb1 = (unsigned short*)carve((size_t)NN * 64 * 2);

    const int EB = (NE + 255) / 256;

    // ---- CSR build (by destination) ----
    hipMemsetAsync(cnt, 0, (size_t)NN * 4, stream);
    hist_rank_kernel<<<EB, 256, 0, stream>>>(dst, cnt, rank);
    scan_block_kernel<<<SCAN_NB, 256, 0, stream>>>(cnt, row_ptr, partial, NN);
    scan_partials_kernel<<<1, 256, 0, stream>>>(partial, pexcl, row_ptr, SCAN_NB);
    scan_add_kernel<<<SCAN_NB, 256, 0, stream>>>(row_ptr, pexcl, NN);
    fill_kernel<<<EB, 256, 0, stream>>>(src, dst, edge_w, row_ptr, rank, erec);

    // ---- weight transposes (fp32 [K][N] -> bf16 [N][K]) ----
    wtrans_kernel<<<(256 * 128 + 255) / 256, 256, 0, stream>>>(W1, W1T, 256, 128);
    wtrans_kernel<<<(128 * 64 + 255) / 256, 256, 0, stream>>>(W2, W2T, 128, 64);

    // ---- conv1: x1 = prop(features @ W1) + b1 ----
    gemm_mfma_kernel<128, 256, false>
        <<<(NN + 63) / 64, 256, 0, stream>>>(features, W1T, y1_bf, NN);
    prop_kernel<128, 0, true>
        <<<(NN * 16 + 255) / 256, 256, 0, stream>>>(row_ptr, erec, y1_bf, b1,
                                                    nullptr, x1_bf);

    // ---- conv2: h = prop(x1 @ W2) + b2 ----
    gemm_mfma_kernel<64, 128, true>
        <<<(NN + 63) / 64, 256, 0, stream>>>(x1_bf, W2T, y2_bf, NN);
    prop_kernel<64, 0, true>
        <<<(NN * 8 + 255) / 256, 256, 0, stream>>>(row_ptr, erec, y2_bf, b2,
                                                   nullptr, h_bf);

    // ---- APPNP: 10 steps of x = 0.9*prop(x) + 0.1*h ----
    const unsigned short* x_cur = h_bf;
    for (int k = 0; k < 9; ++k) {
        unsigned short* out = (k & 1) ? xb1 : xb0;
        prop_kernel<64, 1, true>
            <<<(NN * 8 + 255) / 256, 256, 0, stream>>>(row_ptr, erec, x_cur,
                                                       nullptr, h_bf, out);
        x_cur = out;
    }
    prop_kernel<64, 1, false>
        <<<(NN * 8 + 255) / 256, 256, 0, stream>>>(row_ptr, erec, x_cur, nullptr,
                                                   h_bf, (float*)d_out);

    // ---- second tuple element: the Python int 10 ----
    if (out_size > NN * 64) {
        write_scalar_kernel<<<1, 1, 0, stream>>>((float*)d_out + (size_t)NN * 64,
                                                 10.0f);
    }
}